// Round 1
// baseline (25.398 us; speedup 1.0000x reference)
//
#include <hip/hip_runtime.h>

// CoupledFourierSystem: out[t][j] = b[j] + sum_d W[j][d] * sum_{h,c} A[d][h][c]*cos(w[d][h][c]*s_t + phi[d][h][c])
// S=32768, DIM=64, H=16 (HC=32 harmonics*components per dim)

constexpr int S_PTS = 32768;
constexpr int DIM   = 64;
constexpr int HC    = 32;   // H*2
constexpr int TPW   = 16;   // time points per wave
constexpr float INV_2PI = 0.15915494309189535f;

__global__ __launch_bounds__(256, 2)
void fourier_fused(const float* __restrict__ s,
                   const float* __restrict__ A,
                   const float* __restrict__ phi,
                   const float* __restrict__ w,
                   const float* __restrict__ Wm,
                   const float* __restrict__ b,
                   float* __restrict__ out)
{
    // per-wave double-buffered pre_sol row (wave-synchronous, no __syncthreads needed)
    __shared__ float pres[4][2][DIM];

    const int lane = threadIdx.x & 63;
    const int wid  = threadIdx.x >> 6;
    const int gw   = blockIdx.x * 4 + wid;
    const int t0   = gw * TPW;
    if (t0 >= S_PTS) return;

    // ---- per-lane params: lane plays role d for pre_sol ----
    // pre-scale w, phi by 1/(2*pi) so cos is raw v_cos_f32 (input in revolutions)
    float a_r[HC], w_r[HC], p_r[HC];
    {
        const float4* A4 = reinterpret_cast<const float4*>(A   + lane * HC);
        const float4* P4 = reinterpret_cast<const float4*>(phi + lane * HC);
        const float4* W4 = reinterpret_cast<const float4*>(w   + lane * HC);
        #pragma unroll
        for (int q = 0; q < HC / 4; ++q) {
            float4 av = A4[q], pv = P4[q], wv = W4[q];
            a_r[4*q+0] = av.x; a_r[4*q+1] = av.y; a_r[4*q+2] = av.z; a_r[4*q+3] = av.w;
            p_r[4*q+0] = pv.x * INV_2PI; p_r[4*q+1] = pv.y * INV_2PI;
            p_r[4*q+2] = pv.z * INV_2PI; p_r[4*q+3] = pv.w * INV_2PI;
            w_r[4*q+0] = wv.x * INV_2PI; w_r[4*q+1] = wv.y * INV_2PI;
            w_r[4*q+2] = wv.z * INV_2PI; w_r[4*q+3] = wv.w * INV_2PI;
        }
    }

    // ---- W row in registers: lane plays role j for the output matvec ----
    float Wrow[DIM];
    {
        const float4* Wr4 = reinterpret_cast<const float4*>(Wm + lane * DIM);
        #pragma unroll
        for (int q = 0; q < DIM / 4; ++q) {
            float4 v = Wr4[q];
            Wrow[4*q+0] = v.x; Wrow[4*q+1] = v.y; Wrow[4*q+2] = v.z; Wrow[4*q+3] = v.w;
        }
    }
    const float bj = b[lane];

    // lanes 0..15 hold the wave's 16 time values (others duplicate, harmless)
    const float sv = s[t0 + (lane & (TPW - 1))];

    #pragma unroll 1
    for (int k = 0; k < TPW; ++k) {
        // broadcast s_t to all lanes as an SGPR
        const float st = __uint_as_float(__builtin_amdgcn_readlane(__float_as_uint(sv), k));

        // pre_sol[t][lane] = sum_i a[i] * cos(2*pi*(w_r[i]*st + p_r[i]))
        float ac0 = 0.f, ac1 = 0.f, ac2 = 0.f, ac3 = 0.f;
        #pragma unroll
        for (int i = 0; i < HC; i += 4) {
            ac0 = fmaf(a_r[i+0], __builtin_amdgcn_cosf(fmaf(w_r[i+0], st, p_r[i+0])), ac0);
            ac1 = fmaf(a_r[i+1], __builtin_amdgcn_cosf(fmaf(w_r[i+1], st, p_r[i+1])), ac1);
            ac2 = fmaf(a_r[i+2], __builtin_amdgcn_cosf(fmaf(w_r[i+2], st, p_r[i+2])), ac2);
            ac3 = fmaf(a_r[i+3], __builtin_amdgcn_cosf(fmaf(w_r[i+3], st, p_r[i+3])), ac3);
        }
        const float pre = (ac0 + ac1) + (ac2 + ac3);

        // stage row in LDS, then broadcast-read (uniform addr -> conflict-free)
        float* buf = &pres[wid][k & 1][0];
        buf[lane] = pre;
        asm volatile("s_waitcnt lgkmcnt(0)" ::: "memory");

        float o = bj;
        #pragma unroll
        for (int d = 0; d < DIM; d += 4) {
            float4 p = *reinterpret_cast<const float4*>(buf + d);
            o = fmaf(p.x, Wrow[d+0], o);
            o = fmaf(p.y, Wrow[d+1], o);
            o = fmaf(p.z, Wrow[d+2], o);
            o = fmaf(p.w, Wrow[d+3], o);
        }
        out[(t0 + k) * DIM + lane] = o;  // coalesced 256B per wave
    }
}

extern "C" void kernel_launch(void* const* d_in, const int* in_sizes, int n_in,
                              void* d_out, int out_size, void* d_ws, size_t ws_size,
                              hipStream_t stream) {
    const float* s   = (const float*)d_in[0];
    // d_in[1] is x — unused by the forward pass
    const float* A   = (const float*)d_in[2];
    const float* phi = (const float*)d_in[3];
    const float* w   = (const float*)d_in[4];
    const float* Wm  = (const float*)d_in[5];
    const float* b   = (const float*)d_in[6];
    float* out = (float*)d_out;

    dim3 grid(S_PTS / (4 * TPW));  // 512 blocks, 4 waves each, 16 t per wave
    dim3 block(256);
    hipLaunchKernelGGL(fourier_fused, grid, block, 0, stream,
                       s, A, phi, w, Wm, b, out);
}

// Round 2
// 23.895 us; speedup vs baseline: 1.0629x; 1.0629x over previous
//
#include <hip/hip_runtime.h>

// CoupledFourierSystem: out[t][j] = b[j] + sum_d W[j][d] * sum_{h,c} A[d][h][c]*cos(w[d][h][c]*s_t + phi[d][h][c])
// S=32768, DIM=64, H=16 (HC=32 harmonics*components per dim)
//
// Schedule per wave (lane = d for Fourier, lane = j for matvec):
//   phase A: 16 t's of Fourier sums, pure register VALU (no LDS on critical path)
//   phase B: 16 conflict-free ds_write_b32 + single lgkmcnt(0)
//   phase C: 16 independent matvecs, 4 accumulators each, uniform-addr (broadcast) float4 LDS reads

constexpr int S_PTS = 32768;
constexpr int DIM   = 64;
constexpr int HC    = 32;   // H*2
constexpr int TPW   = 16;   // time points per wave
constexpr float INV_2PI = 0.15915494309189535f;

__global__ __launch_bounds__(256, 2)
void fourier_fused(const float* __restrict__ s,
                   const float* __restrict__ A,
                   const float* __restrict__ phi,
                   const float* __restrict__ w,
                   const float* __restrict__ Wm,
                   const float* __restrict__ b,
                   float* __restrict__ out)
{
    __shared__ float pres[4][TPW][DIM];   // 16 KiB, wave-private slabs

    const int lane = threadIdx.x & 63;
    const int wid  = threadIdx.x >> 6;
    const int gw   = blockIdx.x * 4 + wid;
    const int t0   = gw * TPW;

    // ---- per-lane Fourier params (lane = d), freqs/phases pre-scaled to revolutions ----
    float a_r[HC], w_r[HC], p_r[HC];
    {
        const float4* A4 = reinterpret_cast<const float4*>(A   + lane * HC);
        const float4* P4 = reinterpret_cast<const float4*>(phi + lane * HC);
        const float4* W4 = reinterpret_cast<const float4*>(w   + lane * HC);
        #pragma unroll
        for (int q = 0; q < HC / 4; ++q) {
            float4 av = A4[q], pv = P4[q], wv = W4[q];
            a_r[4*q+0] = av.x; a_r[4*q+1] = av.y; a_r[4*q+2] = av.z; a_r[4*q+3] = av.w;
            p_r[4*q+0] = pv.x * INV_2PI; p_r[4*q+1] = pv.y * INV_2PI;
            p_r[4*q+2] = pv.z * INV_2PI; p_r[4*q+3] = pv.w * INV_2PI;
            w_r[4*q+0] = wv.x * INV_2PI; w_r[4*q+1] = wv.y * INV_2PI;
            w_r[4*q+2] = wv.z * INV_2PI; w_r[4*q+3] = wv.w * INV_2PI;
        }
    }

    // lanes 0..15 hold the wave's 16 time values
    const float sv = s[t0 + (lane & (TPW - 1))];

    // ---- phase A: all 16 Fourier sums into registers ----
    float pr[TPW];
    #pragma unroll
    for (int k = 0; k < TPW; ++k) {
        const float st = __uint_as_float(__builtin_amdgcn_readlane(__float_as_uint(sv), k));
        float ac0 = 0.f, ac1 = 0.f, ac2 = 0.f, ac3 = 0.f;
        #pragma unroll
        for (int i = 0; i < HC; i += 4) {
            ac0 = fmaf(a_r[i+0], __builtin_amdgcn_cosf(fmaf(w_r[i+0], st, p_r[i+0])), ac0);
            ac1 = fmaf(a_r[i+1], __builtin_amdgcn_cosf(fmaf(w_r[i+1], st, p_r[i+1])), ac1);
            ac2 = fmaf(a_r[i+2], __builtin_amdgcn_cosf(fmaf(w_r[i+2], st, p_r[i+2])), ac2);
            ac3 = fmaf(a_r[i+3], __builtin_amdgcn_cosf(fmaf(w_r[i+3], st, p_r[i+3])), ac3);
        }
        pr[k] = (ac0 + ac1) + (ac2 + ac3);
    }

    // ---- phase B: stage the 16x64 pre_sol slab; banks = lane%32 -> 2-way (free) ----
    float* slab = &pres[wid][0][0];
    #pragma unroll
    for (int k = 0; k < TPW; ++k) slab[k * DIM + lane] = pr[k];
    asm volatile("s_waitcnt lgkmcnt(0)" ::: "memory");

    // ---- W row + bias (lane = j); loaded here so it's live only in phase C ----
    float Wrow[DIM];
    {
        const float4* Wr4 = reinterpret_cast<const float4*>(Wm + lane * DIM);
        #pragma unroll
        for (int q = 0; q < DIM / 4; ++q) {
            float4 v = Wr4[q];
            Wrow[4*q+0] = v.x; Wrow[4*q+1] = v.y; Wrow[4*q+2] = v.z; Wrow[4*q+3] = v.w;
        }
    }
    const float bj = b[lane];

    // ---- phase C: 16 independent matvecs, 4 accumulators, broadcast LDS reads ----
    #pragma unroll
    for (int k = 0; k < TPW; ++k) {
        const float* row = slab + k * DIM;
        float o0 = bj, o1 = 0.f, o2 = 0.f, o3 = 0.f;
        #pragma unroll
        for (int d = 0; d < DIM; d += 16) {
            float4 p0 = *reinterpret_cast<const float4*>(row + d + 0);
            float4 p1 = *reinterpret_cast<const float4*>(row + d + 4);
            float4 p2 = *reinterpret_cast<const float4*>(row + d + 8);
            float4 p3 = *reinterpret_cast<const float4*>(row + d + 12);
            o0 = fmaf(p0.x, Wrow[d+ 0], o0); o0 = fmaf(p0.y, Wrow[d+ 1], o0);
            o0 = fmaf(p0.z, Wrow[d+ 2], o0); o0 = fmaf(p0.w, Wrow[d+ 3], o0);
            o1 = fmaf(p1.x, Wrow[d+ 4], o1); o1 = fmaf(p1.y, Wrow[d+ 5], o1);
            o1 = fmaf(p1.z, Wrow[d+ 6], o1); o1 = fmaf(p1.w, Wrow[d+ 7], o1);
            o2 = fmaf(p2.x, Wrow[d+ 8], o2); o2 = fmaf(p2.y, Wrow[d+ 9], o2);
            o2 = fmaf(p2.z, Wrow[d+10], o2); o2 = fmaf(p2.w, Wrow[d+11], o2);
            o3 = fmaf(p3.x, Wrow[d+12], o3); o3 = fmaf(p3.y, Wrow[d+13], o3);
            o3 = fmaf(p3.z, Wrow[d+14], o3); o3 = fmaf(p3.w, Wrow[d+15], o3);
        }
        out[(t0 + k) * DIM + lane] = (o0 + o1) + (o2 + o3);
    }
}

extern "C" void kernel_launch(void* const* d_in, const int* in_sizes, int n_in,
                              void* d_out, int out_size, void* d_ws, size_t ws_size,
                              hipStream_t stream) {
    const float* s   = (const float*)d_in[0];
    // d_in[1] is x — unused by the forward pass
    const float* A   = (const float*)d_in[2];
    const float* phi = (const float*)d_in[3];
    const float* w   = (const float*)d_in[4];
    const float* Wm  = (const float*)d_in[5];
    const float* b   = (const float*)d_in[6];
    float* out = (float*)d_out;

    dim3 grid(S_PTS / (4 * TPW));  // 512 blocks x 4 waves x 16 t = 32768
    dim3 block(256);
    hipLaunchKernelGGL(fourier_fused, grid, block, 0, stream,
                       s, A, phi, w, Wm, b, out);
}